// Round 2
// baseline (584.707 us; speedup 1.0000x reference)
//
#include <hip/hip_runtime.h>

// PowerSpectrum: out[n, l*512 + q*16 + p] = (1/sqrt(2l+1)) * sum_m x_nu[l,n,m,q] * x_1[l,n,m,p]
// L=4, M=7, F_NU=32, F_1=16. Memory-bound: 268.8 MB read + 409.6 MB write vs 1.43 GFLOP.
// Block = 256 threads, 4 samples. For fixed l, 4 consecutive samples are one
// contiguous global chunk (x_nu: 224 float4, x_1: 112 float4) -> trivial staging.

typedef float v4f __attribute__((ext_vector_type(4)));

constexpr int L_DIM = 4, M_DIM = 7, FNU = 32, F1 = 16;
constexpr int XNU_S = M_DIM * FNU;            // 224 floats per (l, sample)
constexpr int X1_S  = M_DIM * F1;             // 112 floats per (l, sample)
constexpr int NS    = 4;                      // samples per block
constexpr int A_LL  = NS * XNU_S;             // 896 floats per l (a region)
constexpr int BOFF  = L_DIM * A_LL;           // 3584 floats: start of b region
constexpr int B_LL  = NS * X1_S + 16;         // 464: +16 pad => l-halves hit complementary banks
constexpr int LDS_F = BOFF + L_DIM * B_LL;    // 5440 floats = 21760 B -> 7 blocks/CU
constexpr int OUT_W = L_DIM * FNU * F1;       // 2048 floats per sample

__global__ __launch_bounds__(256) void ps_kernel(
    const float* __restrict__ x_nu,
    const float* __restrict__ x_1,
    float* __restrict__ out,
    int N)
{
    __shared__ float lds[LDS_F];
    const int t  = threadIdx.x;
    const int n0 = blockIdx.x * NS;

    const float4* __restrict__ xnu4 = reinterpret_cast<const float4*>(x_nu);
    const float4* __restrict__ x14  = reinterpret_cast<const float4*>(x_1);
    float4* lds4 = reinterpret_cast<float4*>(lds);

    if (n0 + NS <= N) {
        // Fast path: per l, one contiguous a-chunk (224 f4) + one b-chunk (112 f4).
        #pragma unroll
        for (int l = 0; l < L_DIM; ++l) {
            const float4* src_a = xnu4 + (size_t)(l * N + n0) * (XNU_S / 4);
            const float4* src_b = x14  + (size_t)(l * N + n0) * (X1_S / 4);
            float4* dst_a = lds4 + l * (A_LL / 4);            // l*224
            float4* dst_b = lds4 + (BOFF / 4) + l * (B_LL / 4); // 896 + l*116
            if (t < 224) dst_a[t] = src_a[t];
            else         dst_b[t - 224] = src_b[t - 224];     // b[0..31]
            int i2 = t + 32;                                   // second pass: b[32..111]
            if (t < 80) dst_b[i2] = src_b[i2];
        }
    } else {
        // Tail block: per-element sample guard.
        for (int i = t; i < L_DIM * NS * (XNU_S + X1_S) / 4; i += 256) {
            int l = i / 336, r = i - l * 336;
            if (r < 224) {
                int s = r / 56, off = r - s * 56;
                if (n0 + s < N)
                    lds4[l * (A_LL / 4) + s * 56 + off] =
                        xnu4[(size_t)(l * N + n0 + s) * 56 + off];
            } else {
                int r2 = r - 224;
                int s = r2 / 28, off = r2 - s * 28;
                if (n0 + s < N)
                    lds4[(BOFF / 4) + l * (B_LL / 4) + s * 28 + off] =
                        x14[(size_t)(l * N + n0 + s) * 28 + off];
            }
        }
    }
    __syncthreads();

    // Thread -> (l, 4q x 4p tile); handles samples {t>>7, (t>>7)+2}.
    const int l     = (t >> 5) & 3;
    const int u     = t & 31;
    const int pb    = (u & 3) * 4;       // p base
    const int q2    = u >> 2;            // q = q2 + 8k
    const int sbase = t >> 7;            // 0..1
    const float scale = rsqrtf(2.0f * (float)l + 1.0f);

    #pragma unroll
    for (int si = 0; si < 2; ++si) {
        const int s = sbase + 2 * si;
        const int n = n0 + s;
        if (n >= N) continue;

        const float* a_s = lds + l * A_LL + s * XNU_S;          // [m*32 + q]
        const float* b_s = lds + BOFF + l * B_LL + s * X1_S;    // [m*16 + p]

        float acc[4][4];
        #pragma unroll
        for (int k = 0; k < 4; ++k)
            #pragma unroll
            for (int j = 0; j < 4; ++j) acc[k][j] = 0.0f;

        #pragma unroll
        for (int m = 0; m < M_DIM; ++m) {
            v4f b = *reinterpret_cast<const v4f*>(&b_s[m * F1 + pb]);   // ds_read_b128
            float a[4];
            #pragma unroll
            for (int k = 0; k < 4; ++k) a[k] = a_s[m * FNU + q2 + 8 * k]; // ds_read_b32 x4 (broadcast/2-way)
            #pragma unroll
            for (int k = 0; k < 4; ++k) {
                acc[k][0] += a[k] * b.x;
                acc[k][1] += a[k] * b.y;
                acc[k][2] += a[k] * b.z;
                acc[k][3] += a[k] * b.w;
            }
        }

        float* outp = out + (size_t)n * OUT_W + l * (FNU * F1);
        #pragma unroll
        for (int k = 0; k < 4; ++k) {
            v4f v = { acc[k][0] * scale, acc[k][1] * scale,
                      acc[k][2] * scale, acc[k][3] * scale };
            // wave store = two contiguous 512B segments -> fully coalesced dwordx4
            __builtin_nontemporal_store(
                v, reinterpret_cast<v4f*>(&outp[(q2 + 8 * k) * F1 + pb]));
        }
    }
}

extern "C" void kernel_launch(void* const* d_in, const int* in_sizes, int n_in,
                              void* d_out, int out_size, void* d_ws, size_t ws_size,
                              hipStream_t stream) {
    const float* x_nu = (const float*)d_in[0];
    const float* x_1  = (const float*)d_in[1];
    float* out = (float*)d_out;
    const int N = in_sizes[0] / (L_DIM * M_DIM * FNU);   // 50000
    const int blocks = (N + NS - 1) / NS;
    ps_kernel<<<blocks, 256, 0, stream>>>(x_nu, x_1, out, N);
}